// Round 1
// 18857.570 us; speedup vs baseline: 2.3021x; 2.3021x over previous
//
#include <hip/hip_runtime.h>
#include <math.h>

#define D 256
#define SEQ 1000
#define NB 32
#define PATCH 160
#define NL 6
#define M_TOTAL (NB * SEQ)   // 32000
#define G3 (3 * D)           // 768

__device__ __forceinline__ float gelu_exact(float v) {
    return 0.5f * v * (1.0f + erff(v * 0.70710678118654752440f));
}

// ---------------------------------------------------------------------------
// Kernel 1: conv patchify GEMM + exact GELU + pos_emb add
// ---------------------------------------------------------------------------
__global__ __launch_bounds__(256) void conv_gelu_pos(
    const float* __restrict__ wav, const float* __restrict__ cw,
    const float* __restrict__ pos, float* __restrict__ x)
{
    __shared__ float As[64][33];
    __shared__ float Bs[32][65];
    const int m0 = blockIdx.x * 64;
    const int n0 = blockIdx.y * 64;
    const int tid = threadIdx.x;
    const int tx = tid & 15;      // 0..15 -> n
    const int ty = tid >> 4;      // 0..15 -> m
    float acc[4][4] = {};

    for (int kc = 0; kc < PATCH; kc += 32) {
        for (int p = 0; p < 8; ++p) {
            int mr = p * 8 + (tid >> 5);
            int kk = tid & 31;
            int m = m0 + mr;
            int b = m / SEQ, s = m % SEQ;
            As[mr][kk] = wav[(size_t)b * 160000 + (size_t)s * PATCH + kc + kk];
        }
        for (int p = 0; p < 8; ++p) {
            int kr = p * 4 + (tid >> 6);
            int nn = tid & 63;
            Bs[kr][nn] = cw[(size_t)(kc + kr) * D + n0 + nn];
        }
        __syncthreads();
        #pragma unroll
        for (int kk = 0; kk < 32; ++kk) {
            float a[4], bb[4];
            #pragma unroll
            for (int i = 0; i < 4; ++i) a[i] = As[ty * 4 + i][kk];
            #pragma unroll
            for (int j = 0; j < 4; ++j) bb[j] = Bs[kk][tx * 4 + j];
            #pragma unroll
            for (int i = 0; i < 4; ++i)
                #pragma unroll
                for (int j = 0; j < 4; ++j)
                    acc[i][j] = fmaf(a[i], bb[j], acc[i][j]);
        }
        __syncthreads();
    }
    #pragma unroll
    for (int i = 0; i < 4; ++i) {
        int m = m0 + ty * 4 + i;
        int s = m % SEQ;
        int n = n0 + tx * 4;
        float4 v;
        v.x = gelu_exact(acc[i][0]) + pos[(size_t)s * D + n + 0];
        v.y = gelu_exact(acc[i][1]) + pos[(size_t)s * D + n + 1];
        v.z = gelu_exact(acc[i][2]) + pos[(size_t)s * D + n + 2];
        v.w = gelu_exact(acc[i][3]) + pos[(size_t)s * D + n + 3];
        *(float4*)&x[(size_t)m * D + n] = v;
    }
}

// ---------------------------------------------------------------------------
// Kernel 2: per-row mean / rstd (LayerNorm stats). One wave per row.
// ---------------------------------------------------------------------------
__global__ __launch_bounds__(64) void row_stats(
    const float* __restrict__ x, float* __restrict__ st)
{
    const int m = blockIdx.x;
    const int t = threadIdx.x;
    const float* r = x + (size_t)m * D;
    float s = 0.f, q = 0.f;
    #pragma unroll
    for (int i = 0; i < 4; ++i) {
        float v = r[t + 64 * i];
        s += v;
        q += v * v;
    }
    #pragma unroll
    for (int o = 32; o > 0; o >>= 1) {
        s += __shfl_down(s, o);
        q += __shfl_down(q, o);
    }
    if (t == 0) {
        float mu = s * (1.f / 256.f);
        float var = q * (1.f / 256.f) - mu * mu;
        st[2 * m]     = mu;
        st[2 * m + 1] = rsqrtf(var + 1e-5f);
    }
}

// ---------------------------------------------------------------------------
// Kernel 3: fused LN + input-projection GEMM
// ---------------------------------------------------------------------------
__global__ __launch_bounds__(256) void ln_xp_gemm(
    const float* __restrict__ x, const float* __restrict__ st,
    const float* __restrict__ lnsc, const float* __restrict__ lnbi,
    const float* __restrict__ wih, const float* __restrict__ bih,
    float* __restrict__ xp)
{
    __shared__ float As[64][33];
    __shared__ float Bs[32][65];
    __shared__ float sc[D], bi[D];
    const int m0 = blockIdx.x * 64;
    const int n0 = blockIdx.y * 64;
    const int tid = threadIdx.x;
    const int tx = tid & 15;
    const int ty = tid >> 4;
    sc[tid] = lnsc[tid];
    bi[tid] = lnbi[tid];
    float acc[4][4] = {};

    for (int kc = 0; kc < D; kc += 32) {
        for (int p = 0; p < 8; ++p) {
            int mr = p * 8 + (tid >> 5);
            int kk = tid & 31;
            int m = m0 + mr;
            float mu = st[2 * m], rs = st[2 * m + 1];
            float v = x[(size_t)m * D + kc + kk];
            As[mr][kk] = (v - mu) * rs * sc[kc + kk] + bi[kc + kk];
        }
        for (int p = 0; p < 8; ++p) {
            int nr = p * 8 + (tid >> 5);
            int kk = tid & 31;
            Bs[kk][nr] = wih[(size_t)(n0 + nr) * D + kc + kk];
        }
        __syncthreads();
        #pragma unroll
        for (int kk = 0; kk < 32; ++kk) {
            float a[4], bb[4];
            #pragma unroll
            for (int i = 0; i < 4; ++i) a[i] = As[ty * 4 + i][kk];
            #pragma unroll
            for (int j = 0; j < 4; ++j) bb[j] = Bs[kk][tx * 4 + j];
            #pragma unroll
            for (int i = 0; i < 4; ++i)
                #pragma unroll
                for (int j = 0; j < 4; ++j)
                    acc[i][j] = fmaf(a[i], bb[j], acc[i][j]);
        }
        __syncthreads();
    }
    #pragma unroll
    for (int i = 0; i < 4; ++i) {
        int m = m0 + ty * 4 + i;
        int n = n0 + tx * 4;
        float4 v;
        v.x = acc[i][0] + bih[n + 0];
        v.y = acc[i][1] + bih[n + 1];
        v.z = acc[i][2] + bih[n + 2];
        v.w = acc[i][3] + bih[n + 3];
        *(float4*)&xp[(size_t)m * G3 + n] = v;
    }
}

// ---------------------------------------------------------------------------
// Kernel 4: transpose w_hh [768][256] -> whT [256][768]
// ---------------------------------------------------------------------------
__global__ __launch_bounds__(256) void transpose_whh(
    const float* __restrict__ whh, float* __restrict__ whT)
{
    __shared__ float t[32][33];
    const int g0 = blockIdx.x * 32;
    const int k0 = blockIdx.y * 32;
    const int lx = threadIdx.x & 31;
    const int ly = threadIdx.x >> 5;   // 0..7
    for (int i = 0; i < 32; i += 8)
        t[ly + i][lx] = whh[(size_t)(g0 + ly + i) * D + k0 + lx];
    __syncthreads();
    for (int i = 0; i < 32; i += 8)
        whT[(size_t)(k0 + ly + i) * G3 + g0 + lx] = t[lx][ly + i];
}

// ---------------------------------------------------------------------------
// Kernel 4b: zero the exchange flags (once per launch; tokens are monotonic
// across all 6 layers within one launch, so a single reset suffices).
// ---------------------------------------------------------------------------
__global__ __launch_bounds__(256) void zero_flags(unsigned int* __restrict__ f)
{
    f[blockIdx.x * 256 + threadIdx.x] = 0u;
}

// ---------------------------------------------------------------------------
// Kernel 5: GRU recurrence, register-resident weights, block-PAIR per batch.
//
// Why: the old kernel streamed all of whT (786 KB) from L2 every timestep and
// sat at the per-CU L2 bandwidth ceiling (~120 GB/s -> 6.6 us/step). Here the
// K dimension is split across TWO blocks (64 blocks total, = pair*2+half);
// each block holds its half of W_hh entirely in VGPRs (192 floats/thread at
// 512 threads), so per-step weight traffic is zero. The two halves exchange
// their 768 partial sums each step through L3 via agent-scope atomics:
//   - write partials (relaxed, agent) -> __syncthreads (drains vmcnt(0))
//   - thread0: release-store token flag; acquire-poll peer flag
//   - read peer partials (relaxed, agent)
// Tokens are monotonic (layer*SEQ + t + 1), flags zeroed once per launch.
// Exchange buffers are double-buffered by t-parity: a block can only reuse
// slot s(t) at t+2 after observing the peer's t+1 flag, which the peer only
// publishes after having consumed slot s(t). No overwrite race.
// Both halves recombine partials in the SAME order (lo-half + hi-half), so
// the duplicated h state is bitwise identical across the pair.
// 64 blocks x 512 thr, <=256 VGPR, 5 KB LDS: trivially co-resident on 256 CUs.
// ---------------------------------------------------------------------------
__global__ __launch_bounds__(512, 2) void gru_scan_pair(
    const float* __restrict__ xp, const float* __restrict__ whT,
    const float* __restrict__ bhh, float* __restrict__ x,
    float* exch, unsigned int* flags, int layer)
{
    __shared__ float hs[2][D];
    __shared__ float pr[3][D];
    const int tid  = threadIdx.x;
    const int d    = tid & 255;
    const int kq   = tid >> 8;              // 0 or 1 (wave-uniform)
    const int pair = blockIdx.x >> 1;       // batch index
    const int half = blockIdx.x & 1;        // K half: [0,128) or [128,256)
    const int kbase = half * 128 + kq * 64;

    // --- load resident weights: 64 k x 3 gates = 192 VGPRs -----------------
    float wr[64], wz[64], wn[64];
    {
        const float* wb = whT + (size_t)kbase * G3 + d;
        #pragma unroll
        for (int k = 0; k < 64; ++k) {
            wr[k] = wb[(size_t)k * G3];
            wz[k] = wb[(size_t)k * G3 + D];
            wn[k] = wb[(size_t)k * G3 + 2 * D];
        }
    }
    const float bh_r = bhh[d];
    const float bh_z = bhh[D + d];
    const float bh_n = bhh[2 * D + d];

    float*       exch_mine = exch + ((size_t)(pair * 2 + half)       * 2) * G3;
    const float* exch_peer = exch + ((size_t)(pair * 2 + (1 - half)) * 2) * G3;
    unsigned int* flag_mine = flags + (size_t)(pair * 2 + half) * 32;
    unsigned int* flag_peer = flags + (size_t)(pair * 2 + (1 - half)) * 32;

    const float* xpb = xp + (size_t)pair * SEQ * G3;
    float* xb = x + (size_t)pair * SEQ * D;

    if (tid < D) hs[0][tid] = 0.f;
    __syncthreads();

    int p = 0;
    const unsigned int tok0 = (unsigned int)layer * SEQ + 1u;
    for (int t = 0; t < SEQ; ++t) {
        const unsigned int token = tok0 + (unsigned int)t;
        const int slot = t & 1;

        // prefetch xp row + residual early; latency hides under FMA phase
        float xr = 0.f, xz = 0.f, xn_ = 0.f, xold = 0.f;
        if (kq == 0) {
            const float* xpt = xpb + (size_t)t * G3;
            xr  = xpt[d];
            xz  = xpt[D + d];
            xn_ = xpt[2 * D + d];
            if (half == 0) xold = xb[(size_t)t * D + d];
        }

        // --- FMA phase: 192 FMAs against register-resident weights ---------
        float ar = 0.f, az = 0.f, an = 0.f;
        const float* hb = &hs[p][kbase];
        #pragma unroll
        for (int q = 0; q < 16; ++q) {
            float4 hv = *(const float4*)(hb + q * 4);   // wave-uniform bcast
            ar = fmaf(hv.x, wr[4*q+0], ar); az = fmaf(hv.x, wz[4*q+0], az); an = fmaf(hv.x, wn[4*q+0], an);
            ar = fmaf(hv.y, wr[4*q+1], ar); az = fmaf(hv.y, wz[4*q+1], az); an = fmaf(hv.y, wn[4*q+1], an);
            ar = fmaf(hv.z, wr[4*q+2], ar); az = fmaf(hv.z, wz[4*q+2], az); an = fmaf(hv.z, wn[4*q+2], an);
            ar = fmaf(hv.w, wr[4*q+3], ar); az = fmaf(hv.w, wz[4*q+3], az); an = fmaf(hv.w, wn[4*q+3], an);
        }

        // --- intra-block reduce (kq=1 -> kq=0) -----------------------------
        if (kq == 1) { pr[0][d] = ar; pr[1][d] = az; pr[2][d] = an; }
        __syncthreads();
        if (kq == 0) {
            ar += pr[0][d]; az += pr[1][d]; an += pr[2][d];
            float* em = exch_mine + (size_t)slot * G3;
            __hip_atomic_store(em + d,         ar, __ATOMIC_RELAXED, __HIP_MEMORY_SCOPE_AGENT);
            __hip_atomic_store(em + D + d,     az, __ATOMIC_RELAXED, __HIP_MEMORY_SCOPE_AGENT);
            __hip_atomic_store(em + 2 * D + d, an, __ATOMIC_RELAXED, __HIP_MEMORY_SCOPE_AGENT);
        }
        __syncthreads();  // implicit s_waitcnt vmcnt(0): exch stores ack'd

        // --- cross-block token handshake -----------------------------------
        if (tid == 0) {
            __hip_atomic_store(flag_mine, token, __ATOMIC_RELEASE, __HIP_MEMORY_SCOPE_AGENT);
            while (__hip_atomic_load(flag_peer, __ATOMIC_ACQUIRE, __HIP_MEMORY_SCOPE_AGENT) < token) { }
        }
        __syncthreads();

        // --- combine + gates (identical summation order in both halves) ----
        if (kq == 0) {
            const float* ep = exch_peer + (size_t)slot * G3;
            float br = __hip_atomic_load(ep + d,         __ATOMIC_RELAXED, __HIP_MEMORY_SCOPE_AGENT);
            float bz = __hip_atomic_load(ep + D + d,     __ATOMIC_RELAXED, __HIP_MEMORY_SCOPE_AGENT);
            float bn = __hip_atomic_load(ep + 2 * D + d, __ATOMIC_RELAXED, __HIP_MEMORY_SCOPE_AGENT);
            float r_lo = (half == 0) ? ar : br, r_hi = (half == 0) ? br : ar;
            float z_lo = (half == 0) ? az : bz, z_hi = (half == 0) ? bz : az;
            float n_lo = (half == 0) ? an : bn, n_hi = (half == 0) ? bn : an;
            float gr = xr + r_lo + r_hi + bh_r;
            float gz = xz + z_lo + z_hi + bh_z;
            float gn =      n_lo + n_hi + bh_n;
            float r = 1.f / (1.f + expf(-gr));
            float z = 1.f / (1.f + expf(-gz));
            float n = tanhf(xn_ + r * gn);
            float hnew = (1.f - z) * n + z * hs[p][d];
            hs[1 - p][d] = hnew;
            if (half == 0) xb[(size_t)t * D + d] = xold + hnew;
        }
        __syncthreads();
        p ^= 1;
    }
}

// ---------------------------------------------------------------------------
// Kernel 6: final LN + mean-pool over sequence
// ---------------------------------------------------------------------------
__global__ __launch_bounds__(256) void pool_ln(
    const float* __restrict__ x, const float* __restrict__ st,
    const float* __restrict__ fsc, const float* __restrict__ fbi,
    float* __restrict__ emb)
{
    const int b = blockIdx.x;
    const int d = threadIdx.x;
    float acc = 0.f;
    for (int s = 0; s < SEQ; ++s) {
        int m = b * SEQ + s;
        acc += (x[(size_t)m * D + d] - st[2 * m]) * st[2 * m + 1];
    }
    emb[b * D + d] = (acc * (1.f / (float)SEQ)) * fsc[d] + fbi[d];
}

// ---------------------------------------------------------------------------
// Kernel 7: classification head (tiny). Single block.
// ---------------------------------------------------------------------------
__global__ __launch_bounds__(256) void head_mlp(
    const float* __restrict__ emb, const float* __restrict__ w1,
    const float* __restrict__ b1, const float* __restrict__ w2,
    const float* __restrict__ b2, float* __restrict__ out)
{
    __shared__ float es[NB][D + 1];
    __shared__ float h1[NB][128 + 1];
    const int t = threadIdx.x;
    for (int i = t; i < NB * D; i += 256) es[i / D][i % D] = emb[i];
    __syncthreads();
    for (int i = t; i < NB * 128; i += 256) {
        int bb = i / 128, j = i % 128;
        float a = b1[j];
        for (int k = 0; k < D; ++k) a = fmaf(es[bb][k], w1[(size_t)k * 128 + j], a);
        h1[bb][j] = gelu_exact(a);
    }
    __syncthreads();
    for (int i = t; i < NB * 8; i += 256) {
        int bb = i / 8, c = i % 8;
        float a = b2[c];
        for (int k = 0; k < 128; ++k) a = fmaf(h1[bb][k], w2[(size_t)k * 8 + c], a);
        out[i] = a;
    }
}

// ---------------------------------------------------------------------------
extern "C" void kernel_launch(void* const* d_in, const int* in_sizes, int n_in,
                              void* d_out, int out_size, void* d_ws, size_t ws_size,
                              hipStream_t stream)
{
    const float* wav  = (const float*)d_in[0];
    const float* cw   = (const float*)d_in[1];
    const float* pos  = (const float*)d_in[2];
    const float* lnsc = (const float*)d_in[3];
    const float* lnbi = (const float*)d_in[4];
    const float* wih  = (const float*)d_in[5];
    const float* whh  = (const float*)d_in[6];
    const float* bih  = (const float*)d_in[7];
    const float* bhh  = (const float*)d_in[8];
    const float* fsc  = (const float*)d_in[9];
    const float* fbi  = (const float*)d_in[10];
    const float* hw1  = (const float*)d_in[11];
    const float* hb1  = (const float*)d_in[12];
    const float* hw2  = (const float*)d_in[13];
    const float* hb2  = (const float*)d_in[14];

    float* ws    = (float*)d_ws;
    float* x     = ws;                        // 8,192,000 f
    float* xp    = x + (size_t)M_TOTAL * D;   // 24,576,000 f
    float* st    = xp + (size_t)M_TOTAL * G3; // 64,000 f
    float* whT   = st + 2 * M_TOTAL;          // 196,608 f
    float* emb   = whT + D * G3;              // 8,192 f
    float* exch  = emb + NB * D;              // 64*2*768 = 98,304 f
    unsigned int* flags = (unsigned int*)(exch + (size_t)64 * 2 * G3); // 2048 u32

    zero_flags<<<8, 256, 0, stream>>>(flags);
    conv_gelu_pos<<<dim3(M_TOTAL / 64, D / 64), 256, 0, stream>>>(wav, cw, pos, x);

    for (int l = 0; l < NL; ++l) {
        row_stats<<<M_TOTAL, 64, 0, stream>>>(x, st);
        ln_xp_gemm<<<dim3(M_TOTAL / 64, G3 / 64), 256, 0, stream>>>(
            x, st, lnsc + (size_t)l * D, lnbi + (size_t)l * D,
            wih + (size_t)l * G3 * D, bih + (size_t)l * G3, xp);
        transpose_whh<<<dim3(G3 / 32, D / 32), 256, 0, stream>>>(
            whh + (size_t)l * G3 * D, whT);
        gru_scan_pair<<<NB * 2, 512, 0, stream>>>(
            xp, whT, bhh + (size_t)l * G3, x, exch, flags, l);
    }

    row_stats<<<M_TOTAL, 64, 0, stream>>>(x, st);
    pool_ln<<<NB, D, 0, stream>>>(x, st, fsc, fbi, emb);
    head_mlp<<<1, 256, 0, stream>>>(emb, hw1, hb1, hw2, hb2, (float*)d_out);
}

// Round 2
// 11991.446 us; speedup vs baseline: 3.6202x; 1.5726x over previous
//
#include <hip/hip_runtime.h>
#include <math.h>

#define D 256
#define SEQ 1000
#define NB 32
#define PATCH 160
#define NL 6
#define M_TOTAL (NB * SEQ)   // 32000
#define G3 (3 * D)           // 768

__device__ __forceinline__ float gelu_exact(float v) {
    return 0.5f * v * (1.0f + erff(v * 0.70710678118654752440f));
}

// ---------------------------------------------------------------------------
// Kernel 1: conv patchify GEMM + exact GELU + pos_emb add
// ---------------------------------------------------------------------------
__global__ __launch_bounds__(256) void conv_gelu_pos(
    const float* __restrict__ wav, const float* __restrict__ cw,
    const float* __restrict__ pos, float* __restrict__ x)
{
    __shared__ float As[64][33];
    __shared__ float Bs[32][65];
    const int m0 = blockIdx.x * 64;
    const int n0 = blockIdx.y * 64;
    const int tid = threadIdx.x;
    const int tx = tid & 15;      // 0..15 -> n
    const int ty = tid >> 4;      // 0..15 -> m
    float acc[4][4] = {};

    for (int kc = 0; kc < PATCH; kc += 32) {
        for (int p = 0; p < 8; ++p) {
            int mr = p * 8 + (tid >> 5);
            int kk = tid & 31;
            int m = m0 + mr;
            int b = m / SEQ, s = m % SEQ;
            As[mr][kk] = wav[(size_t)b * 160000 + (size_t)s * PATCH + kc + kk];
        }
        for (int p = 0; p < 8; ++p) {
            int kr = p * 4 + (tid >> 6);
            int nn = tid & 63;
            Bs[kr][nn] = cw[(size_t)(kc + kr) * D + n0 + nn];
        }
        __syncthreads();
        #pragma unroll
        for (int kk = 0; kk < 32; ++kk) {
            float a[4], bb[4];
            #pragma unroll
            for (int i = 0; i < 4; ++i) a[i] = As[ty * 4 + i][kk];
            #pragma unroll
            for (int j = 0; j < 4; ++j) bb[j] = Bs[kk][tx * 4 + j];
            #pragma unroll
            for (int i = 0; i < 4; ++i)
                #pragma unroll
                for (int j = 0; j < 4; ++j)
                    acc[i][j] = fmaf(a[i], bb[j], acc[i][j]);
        }
        __syncthreads();
    }
    #pragma unroll
    for (int i = 0; i < 4; ++i) {
        int m = m0 + ty * 4 + i;
        int s = m % SEQ;
        int n = n0 + tx * 4;
        float4 v;
        v.x = gelu_exact(acc[i][0]) + pos[(size_t)s * D + n + 0];
        v.y = gelu_exact(acc[i][1]) + pos[(size_t)s * D + n + 1];
        v.z = gelu_exact(acc[i][2]) + pos[(size_t)s * D + n + 2];
        v.w = gelu_exact(acc[i][3]) + pos[(size_t)s * D + n + 3];
        *(float4*)&x[(size_t)m * D + n] = v;
    }
}

// ---------------------------------------------------------------------------
// Kernel 2: per-row mean / rstd (LayerNorm stats). One wave per row.
// ---------------------------------------------------------------------------
__global__ __launch_bounds__(64) void row_stats(
    const float* __restrict__ x, float* __restrict__ st)
{
    const int m = blockIdx.x;
    const int t = threadIdx.x;
    const float* r = x + (size_t)m * D;
    float s = 0.f, q = 0.f;
    #pragma unroll
    for (int i = 0; i < 4; ++i) {
        float v = r[t + 64 * i];
        s += v;
        q += v * v;
    }
    #pragma unroll
    for (int o = 32; o > 0; o >>= 1) {
        s += __shfl_down(s, o);
        q += __shfl_down(q, o);
    }
    if (t == 0) {
        float mu = s * (1.f / 256.f);
        float var = q * (1.f / 256.f) - mu * mu;
        st[2 * m]     = mu;
        st[2 * m + 1] = rsqrtf(var + 1e-5f);
    }
}

// ---------------------------------------------------------------------------
// Kernel 3: fused LN + input-projection GEMM
// ---------------------------------------------------------------------------
__global__ __launch_bounds__(256) void ln_xp_gemm(
    const float* __restrict__ x, const float* __restrict__ st,
    const float* __restrict__ lnsc, const float* __restrict__ lnbi,
    const float* __restrict__ wih, const float* __restrict__ bih,
    float* __restrict__ xp)
{
    __shared__ float As[64][33];
    __shared__ float Bs[32][65];
    __shared__ float sc[D], bi[D];
    const int m0 = blockIdx.x * 64;
    const int n0 = blockIdx.y * 64;
    const int tid = threadIdx.x;
    const int tx = tid & 15;
    const int ty = tid >> 4;
    sc[tid] = lnsc[tid];
    bi[tid] = lnbi[tid];
    float acc[4][4] = {};

    for (int kc = 0; kc < D; kc += 32) {
        for (int p = 0; p < 8; ++p) {
            int mr = p * 8 + (tid >> 5);
            int kk = tid & 31;
            int m = m0 + mr;
            float mu = st[2 * m], rs = st[2 * m + 1];
            float v = x[(size_t)m * D + kc + kk];
            As[mr][kk] = (v - mu) * rs * sc[kc + kk] + bi[kc + kk];
        }
        for (int p = 0; p < 8; ++p) {
            int nr = p * 8 + (tid >> 5);
            int kk = tid & 31;
            Bs[kk][nr] = wih[(size_t)(n0 + nr) * D + kc + kk];
        }
        __syncthreads();
        #pragma unroll
        for (int kk = 0; kk < 32; ++kk) {
            float a[4], bb[4];
            #pragma unroll
            for (int i = 0; i < 4; ++i) a[i] = As[ty * 4 + i][kk];
            #pragma unroll
            for (int j = 0; j < 4; ++j) bb[j] = Bs[kk][tx * 4 + j];
            #pragma unroll
            for (int i = 0; i < 4; ++i)
                #pragma unroll
                for (int j = 0; j < 4; ++j)
                    acc[i][j] = fmaf(a[i], bb[j], acc[i][j]);
        }
        __syncthreads();
    }
    #pragma unroll
    for (int i = 0; i < 4; ++i) {
        int m = m0 + ty * 4 + i;
        int n = n0 + tx * 4;
        float4 v;
        v.x = acc[i][0] + bih[n + 0];
        v.y = acc[i][1] + bih[n + 1];
        v.z = acc[i][2] + bih[n + 2];
        v.w = acc[i][3] + bih[n + 3];
        *(float4*)&xp[(size_t)m * G3 + n] = v;
    }
}

// ---------------------------------------------------------------------------
// Kernel 4: transpose w_hh [768][256] -> whT [256][768]
// ---------------------------------------------------------------------------
__global__ __launch_bounds__(256) void transpose_whh(
    const float* __restrict__ whh, float* __restrict__ whT)
{
    __shared__ float t[32][33];
    const int g0 = blockIdx.x * 32;
    const int k0 = blockIdx.y * 32;
    const int lx = threadIdx.x & 31;
    const int ly = threadIdx.x >> 5;   // 0..7
    for (int i = 0; i < 32; i += 8)
        t[ly + i][lx] = whh[(size_t)(g0 + ly + i) * D + k0 + lx];
    __syncthreads();
    for (int i = 0; i < 32; i += 8)
        whT[(size_t)(k0 + ly + i) * G3 + g0 + lx] = t[lx][ly + i];
}

// ---------------------------------------------------------------------------
// Kernel 4b: zero the exchange buffer (once per launch). Tokens are exact-
// matched per (layer,step), so a zeroed buffer can never alias a live token.
// ---------------------------------------------------------------------------
__global__ __launch_bounds__(256) void zero_exch(unsigned long long* __restrict__ e)
{
    e[blockIdx.x * 256 + threadIdx.x] = 0ull;
}

// ---------------------------------------------------------------------------
// Kernel 5: GRU recurrence, register-resident weights, OUTPUT-dim split pair.
//
// Round-1 post-mortem: the K-split exchange of partial sums cost 3 serialized
// agent-scope round trips per step (store-drain, flag, data) ~= 2 us of the
// 2.86 us step. This version:
//   - splits the pair by OUTPUT dims: block half computes h_new for
//     dout in half*128+[0,128) over the FULL K=256 (no partial-sum exchange;
//     the exchanged quantity is the final h itself, 128 values).
//   - packs each exchanged h value with its step token into ONE 64-bit
//     relaxed agent-scope atomic word (hi32=token, lo32=float bits). The
//     payload is self-validating: no store-drain, no flag, no acquire/release.
//     Critical path = single one-way publish->pickup.
//   - a dedicated poller group (kq==1, its own wave) picks up the peer's 128
//     words WHILE kq==0 computes sigmoid/tanh, overlapping transit with math.
// Race-freedom: parity double-buffer (slot t&1) + exact token match. A block
// overwrites slot(t) first at t+2; reaching t+2 requires having read peer's
// t+1, which peer only publishes after consuming our t. Induction holds from
// t=0. Buffer zeroed per launch => no cross-launch stale-token aliasing.
// Thread layout: tid = kq*128+dd, kq in 0..3. Each thread: gates r,z,n of
// dout=half*128+dd over K quarter [kq*64,kq*64+64) -> 192 weight floats in
// VGPR/AGPR (unified file). LDS reduce kq1..3 -> kq0, then kq0 finalizes.
// ---------------------------------------------------------------------------
__global__ __launch_bounds__(512, 2) void gru_scan_pair(
    const float* __restrict__ xp, const float* __restrict__ whT,
    const float* __restrict__ bhh, float* __restrict__ x,
    unsigned long long* exch, int layer)
{
    __shared__ float h_lds[D];            // full h(t): own half + peer half
    __shared__ float pr[3][3][128];       // [kq-1][gate][dd] partial sums
    const int tid  = threadIdx.x;
    const int kq   = tid >> 7;            // 0..3 (wave-uniform: 2 waves/kq)
    const int dd   = tid & 127;
    const int pair = blockIdx.x >> 1;     // batch index
    const int half = blockIdx.x & 1;      // output-dim half
    const int dout = half * 128 + dd;
    const int k0   = kq * 64;

    // --- resident weights: gates r,z,n of dout, K quarter = 192 floats -----
    float wr[64], wz[64], wn[64];
    {
        const float* wb = whT + (size_t)k0 * G3 + dout;
        #pragma unroll
        for (int k = 0; k < 64; ++k) {
            wr[k] = wb[(size_t)k * G3];
            wz[k] = wb[(size_t)k * G3 + D];
            wn[k] = wb[(size_t)k * G3 + 2 * D];
        }
    }
    const float bh_r = bhh[dout];
    const float bh_z = bhh[D + dout];
    const float bh_n = bhh[2 * D + dout];

    unsigned long long*       pub = exch + (size_t)(pair * 2 + half)       * 2 * 128;
    const unsigned long long* sub = exch + (size_t)(pair * 2 + (1 - half)) * 2 * 128;

    const float* xpb = xp + (size_t)pair * SEQ * G3;
    float* xb = x + (size_t)pair * SEQ * D;

    if (tid < D) h_lds[tid] = 0.f;
    __syncthreads();

    const unsigned int tok0 = (unsigned int)layer * SEQ + 1u;
    for (int t = 0; t < SEQ; ++t) {
        const unsigned int token = tok0 + (unsigned int)t;
        const int par = t & 1;

        // issue xp + residual loads early; latency hides under the FMA phase
        float xr = 0.f, xz = 0.f, xn_ = 0.f, xold = 0.f;
        if (kq == 0) {
            const float* xpt = xpb + (size_t)t * G3;
            xr   = xpt[dout];
            xz   = xpt[D + dout];
            xn_  = xpt[2 * D + dout];
            xold = xb[(size_t)t * D + dout];
        }

        // --- FMA phase: 192 FMAs against resident weights ------------------
        float ar = 0.f, az = 0.f, an = 0.f;
        #pragma unroll
        for (int q = 0; q < 16; ++q) {
            float4 hv = *(const float4*)&h_lds[k0 + q * 4];  // wave-uniform bcast
            ar = fmaf(hv.x, wr[4*q+0], ar); az = fmaf(hv.x, wz[4*q+0], az); an = fmaf(hv.x, wn[4*q+0], an);
            ar = fmaf(hv.y, wr[4*q+1], ar); az = fmaf(hv.y, wz[4*q+1], az); an = fmaf(hv.y, wn[4*q+1], an);
            ar = fmaf(hv.z, wr[4*q+2], ar); az = fmaf(hv.z, wz[4*q+2], az); an = fmaf(hv.z, wn[4*q+2], an);
            ar = fmaf(hv.w, wr[4*q+3], ar); az = fmaf(hv.w, wz[4*q+3], az); an = fmaf(hv.w, wn[4*q+3], an);
        }
        if (kq) { pr[kq-1][0][dd] = ar; pr[kq-1][1][dd] = az; pr[kq-1][2][dd] = an; }
        __syncthreads();

        if (kq == 0) {
            // combine K quarters in fixed order 0,1,2,3 (deterministic)
            ar += pr[0][0][dd] + pr[1][0][dd] + pr[2][0][dd];
            az += pr[0][1][dd] + pr[1][1][dd] + pr[2][1][dd];
            an += pr[0][2][dd] + pr[1][2][dd] + pr[2][2][dd];
            float r = 1.f / (1.f + expf(-(xr + ar + bh_r)));
            float z = 1.f / (1.f + expf(-(xz + az + bh_z)));
            float n = tanhf(xn_ + r * (an + bh_n));
            float hnew = (1.f - z) * n + z * h_lds[dout];
            // publish FIRST (peer's pickup is the critical path), then local
            unsigned long long w =
                ((unsigned long long)token << 32) | (unsigned long long)__float_as_uint(hnew);
            __hip_atomic_store(&pub[par * 128 + dd], w,
                               __ATOMIC_RELAXED, __HIP_MEMORY_SCOPE_AGENT);
            h_lds[dout] = hnew;
            xb[(size_t)t * D + dout] = xold + hnew;
        } else if (kq == 1) {
            // poller wave: pick up peer's 128 h words for this step
            const unsigned long long* qw = &sub[par * 128 + dd];
            unsigned long long w;
            do {
                w = __hip_atomic_load(qw, __ATOMIC_RELAXED, __HIP_MEMORY_SCOPE_AGENT);
            } while ((unsigned int)(w >> 32) != token);
            h_lds[(1 - half) * 128 + dd] = __uint_as_float((unsigned int)w);
        }
        __syncthreads();
    }
}

// ---------------------------------------------------------------------------
// Kernel 6: final LN + mean-pool over sequence
// ---------------------------------------------------------------------------
__global__ __launch_bounds__(256) void pool_ln(
    const float* __restrict__ x, const float* __restrict__ st,
    const float* __restrict__ fsc, const float* __restrict__ fbi,
    float* __restrict__ emb)
{
    const int b = blockIdx.x;
    const int d = threadIdx.x;
    float acc = 0.f;
    for (int s = 0; s < SEQ; ++s) {
        int m = b * SEQ + s;
        acc += (x[(size_t)m * D + d] - st[2 * m]) * st[2 * m + 1];
    }
    emb[b * D + d] = (acc * (1.f / (float)SEQ)) * fsc[d] + fbi[d];
}

// ---------------------------------------------------------------------------
// Kernel 7: classification head (tiny). Single block.
// ---------------------------------------------------------------------------
__global__ __launch_bounds__(256) void head_mlp(
    const float* __restrict__ emb, const float* __restrict__ w1,
    const float* __restrict__ b1, const float* __restrict__ w2,
    const float* __restrict__ b2, float* __restrict__ out)
{
    __shared__ float es[NB][D + 1];
    __shared__ float h1[NB][128 + 1];
    const int t = threadIdx.x;
    for (int i = t; i < NB * D; i += 256) es[i / D][i % D] = emb[i];
    __syncthreads();
    for (int i = t; i < NB * 128; i += 256) {
        int bb = i / 128, j = i % 128;
        float a = b1[j];
        for (int k = 0; k < D; ++k) a = fmaf(es[bb][k], w1[(size_t)k * 128 + j], a);
        h1[bb][j] = gelu_exact(a);
    }
    __syncthreads();
    for (int i = t; i < NB * 8; i += 256) {
        int bb = i / 8, c = i % 8;
        float a = b2[c];
        for (int k = 0; k < 128; ++k) a = fmaf(h1[bb][k], w2[(size_t)k * 8 + c], a);
        out[i] = a;
    }
}

// ---------------------------------------------------------------------------
extern "C" void kernel_launch(void* const* d_in, const int* in_sizes, int n_in,
                              void* d_out, int out_size, void* d_ws, size_t ws_size,
                              hipStream_t stream)
{
    const float* wav  = (const float*)d_in[0];
    const float* cw   = (const float*)d_in[1];
    const float* pos  = (const float*)d_in[2];
    const float* lnsc = (const float*)d_in[3];
    const float* lnbi = (const float*)d_in[4];
    const float* wih  = (const float*)d_in[5];
    const float* whh  = (const float*)d_in[6];
    const float* bih  = (const float*)d_in[7];
    const float* bhh  = (const float*)d_in[8];
    const float* fsc  = (const float*)d_in[9];
    const float* fbi  = (const float*)d_in[10];
    const float* hw1  = (const float*)d_in[11];
    const float* hb1  = (const float*)d_in[12];
    const float* hw2  = (const float*)d_in[13];
    const float* hb2  = (const float*)d_in[14];

    float* ws    = (float*)d_ws;
    float* x     = ws;                        // 8,192,000 f
    float* xp    = x + (size_t)M_TOTAL * D;   // 24,576,000 f
    float* st    = xp + (size_t)M_TOTAL * G3; // 64,000 f
    float* whT   = st + 2 * M_TOTAL;          // 196,608 f
    float* emb   = whT + D * G3;              // 8,192 f
    unsigned long long* exch = (unsigned long long*)(emb + NB * D); // 64*2*128 u64 = 128 KiB

    zero_exch<<<64, 256, 0, stream>>>(exch);  // 16384 u64
    conv_gelu_pos<<<dim3(M_TOTAL / 64, D / 64), 256, 0, stream>>>(wav, cw, pos, x);

    for (int l = 0; l < NL; ++l) {
        row_stats<<<M_TOTAL, 64, 0, stream>>>(x, st);
        ln_xp_gemm<<<dim3(M_TOTAL / 64, G3 / 64), 256, 0, stream>>>(
            x, st, lnsc + (size_t)l * D, lnbi + (size_t)l * D,
            wih + (size_t)l * G3 * D, bih + (size_t)l * G3, xp);
        transpose_whh<<<dim3(G3 / 32, D / 32), 256, 0, stream>>>(
            whh + (size_t)l * G3 * D, whT);
        gru_scan_pair<<<NB * 2, 512, 0, stream>>>(
            xp, whT, bhh + (size_t)l * G3, x, exch, l);
    }

    row_stats<<<M_TOTAL, 64, 0, stream>>>(x, st);
    pool_ln<<<NB, D, 0, stream>>>(x, st, fsc, fbi, emb);
    head_mlp<<<1, 256, 0, stream>>>(emb, hw1, hb1, hw2, hb2, (float*)d_out);
}